// Round 1
// baseline (303.315 us; speedup 1.0000x reference)
//
#include <hip/hip_runtime.h>

// Problem constants (from reference)
#define BSZ 512
#define NC  4
#define NN  16384
#define H2  (0.0078125f * 0.0078125f)   // H*H = 1/16384

#define BLK 512   // threads per block (8 waves)

// Accumulator layout:
// acc[0..9]   = G upper triangle: 00,01,02,03,11,12,13,22,23,33
// acc[10..25] = T[i][m] = acc[10 + 4*i + m]
__device__ __forceinline__ void accum_elem(float a,
                                           float p0, float p1, float p2, float p3,
                                           float tx, float ty, float tz, float tw,
                                           float* acc)
{
    float ap0 = a * p0, ap1 = a * p1, ap2 = a * p2, ap3 = a * p3;
    acc[0]  += ap0 * p0;  acc[1]  += ap0 * p1;  acc[2]  += ap0 * p2;  acc[3]  += ap0 * p3;
    acc[4]  += ap1 * p1;  acc[5]  += ap1 * p2;  acc[6]  += ap1 * p3;
    acc[7]  += ap2 * p2;  acc[8]  += ap2 * p3;
    acc[9]  += ap3 * p3;
    acc[10] += ap0 * tx;  acc[11] += ap0 * ty;  acc[12] += ap0 * tz;  acc[13] += ap0 * tw;
    acc[14] += ap1 * tx;  acc[15] += ap1 * ty;  acc[16] += ap1 * tz;  acc[17] += ap1 * tw;
    acc[18] += ap2 * tx;  acc[19] += ap2 * ty;  acc[20] += ap2 * tz;  acc[21] += ap2 * tw;
    acc[22] += ap3 * tx;  acc[23] += ap3 * ty;  acc[24] += ap3 * tz;  acc[25] += ap3 * tw;
}

__global__ __launch_bounds__(BLK)
void loss_main(const float* __restrict__ coef,
               const float* __restrict__ pred,
               const float* __restrict__ targ,
               float* __restrict__ per_sample)
{
    const int b   = blockIdx.x;
    const int tid = threadIdx.x;

    const float4* __restrict__ c4 = (const float4*)(coef + (size_t)b * NN);
    const float4* __restrict__ q0 = (const float4*)(pred + (size_t)b * NC * NN + 0 * NN);
    const float4* __restrict__ q1 = (const float4*)(pred + (size_t)b * NC * NN + 1 * NN);
    const float4* __restrict__ q2 = (const float4*)(pred + (size_t)b * NC * NN + 2 * NN);
    const float4* __restrict__ q3 = (const float4*)(pred + (size_t)b * NC * NN + 3 * NN);
    const float4* __restrict__ t4 = (const float4*)(targ + (size_t)b * NN * NC);

    float acc[26];
#pragma unroll
    for (int k = 0; k < 26; ++k) acc[k] = 0.f;

    // N/4 = 4096 float4 groups; BLK=512 threads -> 8 iterations/thread
    for (int i = tid; i < NN / 4; i += BLK) {
        float4 cc = c4[i];
        float4 a0 = q0[i];
        float4 a1 = q1[i];
        float4 a2 = q2[i];
        float4 a3 = q3[i];
        // targets: element n is float4 index n; this group covers n = 4i..4i+3
        float4 t0 = t4[4 * i + 0];
        float4 t1 = t4[4 * i + 1];
        float4 t2 = t4[4 * i + 2];
        float4 t3 = t4[4 * i + 3];

        accum_elem(H2 * cc.x, a0.x, a1.x, a2.x, a3.x, t0.x, t0.y, t0.z, t0.w, acc);
        accum_elem(H2 * cc.y, a0.y, a1.y, a2.y, a3.y, t1.x, t1.y, t1.z, t1.w, acc);
        accum_elem(H2 * cc.z, a0.z, a1.z, a2.z, a3.z, t2.x, t2.y, t2.z, t2.w, acc);
        accum_elem(H2 * cc.w, a0.w, a1.w, a2.w, a3.w, t3.x, t3.y, t3.z, t3.w, acc);
    }

    // Block reduction: wave shuffle -> LDS (8 waves) -> thread 0
    const int lane = tid & 63;
    const int wv   = tid >> 6;
    __shared__ float red[26][8];

#pragma unroll
    for (int k = 0; k < 26; ++k) {
        float v = acc[k];
#pragma unroll
        for (int o = 32; o > 0; o >>= 1) v += __shfl_down(v, o, 64);
        if (lane == 0) red[k][wv] = v;
    }
    __syncthreads();

    if (tid == 0) {
        float s[26];
#pragma unroll
        for (int k = 0; k < 26; ++k) {
            float v = 0.f;
#pragma unroll
            for (int w = 0; w < 8; ++w) v += red[k][w];
            s[k] = v;
        }

        float Gm[4][4];
        Gm[0][0] = s[0];
        Gm[0][1] = Gm[1][0] = s[1];
        Gm[0][2] = Gm[2][0] = s[2];
        Gm[0][3] = Gm[3][0] = s[3];
        Gm[1][1] = s[4];
        Gm[1][2] = Gm[2][1] = s[5];
        Gm[1][3] = Gm[3][1] = s[6];
        Gm[2][2] = s[7];
        Gm[2][3] = Gm[3][2] = s[8];
        Gm[3][3] = s[9];

        float Tm[4][4];
#pragma unroll
        for (int i = 0; i < 4; ++i)
#pragma unroll
            for (int m = 0; m < 4; ++m) Tm[i][m] = s[10 + 4 * i + m];

        // Modified Gram-Schmidt in 4-dim coefficient space.
        // u[j][*] = coefficients of orthonormal e_j in terms of p_0..p_3
        float u[4][4];
#pragma unroll
        for (int j = 0; j < 4; ++j) {
            float w[4];
#pragma unroll
            for (int i = 0; i < 4; ++i) w[i] = (i == j) ? 1.f : 0.f;
#pragma unroll
            for (int k = 0; k < 4; ++k) {
                if (k < j) {
                    // proj = <v, e_k>_a = w^T G u_k  (modified GS: uses current w)
                    float proj = 0.f;
#pragma unroll
                    for (int i = 0; i < 4; ++i) {
                        float gu = 0.f;
#pragma unroll
                        for (int l = 0; l < 4; ++l) gu += Gm[i][l] * u[k][l];
                        proj += w[i] * gu;
                    }
#pragma unroll
                    for (int i = 0; i < 4; ++i) w[i] -= proj * u[k][i];
                }
            }
            float n2 = 0.f;
#pragma unroll
            for (int i = 0; i < 4; ++i) {
                float gw = 0.f;
#pragma unroll
                for (int l = 0; l < 4; ++l) gw += Gm[i][l] * w[l];
                n2 += w[i] * gw;
            }
            float sc = (n2 > 0.f) ? rsqrtf(n2) : 1.f;
#pragma unroll
            for (int i = 0; i < 4; ++i) u[j][i] = w[i] * sc;
        }

        // M[c][m] = sum_i u[c][i] * T[i][m]; loss = (4 - sum M^2)/4
        float ssum = 0.f;
#pragma unroll
        for (int c = 0; c < 4; ++c) {
#pragma unroll
            for (int m = 0; m < 4; ++m) {
                float M = 0.f;
#pragma unroll
                for (int i = 0; i < 4; ++i) M += u[c][i] * Tm[i][m];
                ssum += M * M;
            }
        }
        per_sample[b] = (4.f - ssum) * 0.25f;
    }
}

__global__ __launch_bounds__(BSZ)
void reduce_final(const float* __restrict__ ps, float* __restrict__ out)
{
    const int tid = threadIdx.x;   // BSZ = 512 threads, one per sample
    float v = ps[tid];
#pragma unroll
    for (int o = 32; o > 0; o >>= 1) v += __shfl_down(v, o, 64);
    __shared__ float red[8];
    if ((tid & 63) == 0) red[tid >> 6] = v;
    __syncthreads();
    if (tid == 0) {
        float ssum = 0.f;
#pragma unroll
        for (int w = 0; w < 8; ++w) ssum += red[w];
        out[0] = ssum / (float)BSZ;
    }
}

extern "C" void kernel_launch(void* const* d_in, const int* in_sizes, int n_in,
                              void* d_out, int out_size, void* d_ws, size_t ws_size,
                              hipStream_t stream)
{
    const float* coef = (const float*)d_in[0];   // (B, N)
    const float* pred = (const float*)d_in[1];   // (B, C, N)
    const float* targ = (const float*)d_in[2];   // (B, N, C)
    float* out = (float*)d_out;                  // scalar
    float* ps  = (float*)d_ws;                   // per-sample scratch (B floats)

    loss_main<<<BSZ, BLK, 0, stream>>>(coef, pred, targ, ps);
    reduce_final<<<1, BSZ, 0, stream>>>(ps, out);
}